// Round 8
// baseline (229.731 us; speedup 1.0000x reference)
//
#include <hip/hip_runtime.h>
#include <hip/hip_bf16.h>
#include <stdint.h>

#define Hdim 512
#define KC   32768

typedef __hip_bfloat16 bf16;
typedef __attribute__((ext_vector_type(8))) short short8;
typedef __attribute__((ext_vector_type(4))) float float4v;

// pack two fp32 -> two bf16 (truncation) in one v_perm_b32; low16 = trunc(e0)
__device__ __forceinline__ unsigned int pack_bf16_trunc(float e0, float e1) {
  union { float f; unsigned int u; } a, b;
  a.f = e0; b.f = e1;
  return __builtin_amdgcn_perm(b.u, a.u, 0x07060302u);
}

// ---- launch 1: prep partials (0..191 gates, 192..255 awi) + WT transpose (256..319) ----
// Small 64x64 tiles -> 320 blocks: streams the 8 MB of weights with full-GPU parallelism
// (the old 8-block version was ~30-40 us of latency-bound streaming).
__global__ __launch_bounds__(256) void prep_wt_kernel(
    const float* __restrict__ input_, const float* __restrict__ h_0,
    const float* __restrict__ w_ih, const float* __restrict__ w_hh,
    const float* __restrict__ a_w_ih, const float* __restrict__ a_w_hh,
    float* __restrict__ gates_part, float* __restrict__ awi_part,
    bf16* __restrict__ wt) {
  __shared__ float sh[64 * 65];
  const int t = threadIdx.x;
  const int b = blockIdx.x;
  if (b < 192) {               // gates partials: jt 0..23 (64 j), dc 0..7 (64 d)
    const int jt = b % 24, dc = b / 24;
    const int jl = t & 63, dq = t >> 6;
    const int j = jt * 64 + jl;
    float acc = 0.f;
#pragma unroll
    for (int i = 0; i < 16; ++i) {
      const int d = dc * 64 + dq * 16 + i;
      acc += h_0[d] * w_hh[(size_t)d * 1536 + j] + input_[d] * w_ih[(size_t)d * 1536 + j];
    }
    sh[dq * 64 + jl] = acc;
    __syncthreads();
    if (t < 64)
      gates_part[dc * 1536 + jt * 64 + t] = sh[t] + sh[64 + t] + sh[128 + t] + sh[192 + t];
  } else if (b < 256) {        // awi partials: jt 0..7, dc 0..7
    const int b2 = b - 192;
    const int jt = b2 & 7, dc = b2 >> 3;
    const int jl = t & 63, dq = t >> 6;
    const int j = jt * 64 + jl;
    float acc = 0.f;
#pragma unroll
    for (int i = 0; i < 16; ++i) {
      const int d = dc * 64 + dq * 16 + i;
      acc += input_[d] * a_w_ih[(size_t)d * Hdim + j];
    }
    sh[dq * 64 + jl] = acc;
    __syncthreads();
    if (t < 64)
      awi_part[dc * Hdim + jt * 64 + t] = sh[t] + sh[64 + t] + sh[128 + t] + sh[192 + t];
  } else {                     // WT[h][d] = bf16(W[d][h])
    const int b3 = b - 256;
    const int d0 = (b3 & 7) * 64, h0 = (b3 >> 3) * 64;
    const int tx = t & 63, tw = t >> 6;
    float (*tile)[65] = (float (*)[65])sh;
#pragma unroll
    for (int r = 0; r < 16; ++r) {
      const int row = r * 4 + tw;
      tile[row][tx] = a_w_hh[(size_t)(d0 + row) * Hdim + h0 + tx];
    }
    __syncthreads();
#pragma unroll
    for (int r = 0; r < 16; ++r) {
      const int row = r * 4 + tw;
      wt[(size_t)(h0 + row) * Hdim + d0 + tx] = __float2bfloat16(tile[tx][row]);
    }
  }
}

// ---- launch 2: B-resident barrier-free fused GEMM + sigmoid/exp reduce ----
// 2048 blocks x 256 thr (4 waves, 2m x 2n). Block tile 128m x 64n.
// B (64 n-rows x full K=512, bf16) staged ONCE into 64 KB LDS (granule-XOR swizzle),
// then the K-loop has ZERO barriers: A-frags load direct from global (per-lane 32B
// contiguous) with distance-1 register prefetch that nothing blocks.
__global__ __launch_bounds__(256, 2) void gemm_reduce_kernel(
    const float* __restrict__ c_input, const bf16* __restrict__ WT,
    const float* __restrict__ awi_part,
    float* __restrict__ sw_g, float* __restrict__ swc_g) {
  extern __shared__ __align__(16) char BsB[];   // 64 rows x 1024 B, swizzled

  const int tid  = threadIdx.x;
  const int lane = tid & 63;
  const int wv   = tid >> 6;
  const int wm   = wv & 1;     // m half (64 rows)
  const int wn   = wv >> 1;    // n half (32 cols)
  const int lm   = lane & 15;
  const int lq   = lane >> 4;

  // XCD swizzle: 8 n-sharers of one kk-slab have the same id&7 -> same XCD
  const int id     = blockIdx.x;
  const int kk_idx = ((id >> 6) << 3) | (id & 7);   // 0..255
  const int ng     = (id >> 3) & 7;                 // 0..7
  const int kk0 = kk_idx * 128;
  const int n0  = ng * 64;

  // --- stage B resident (the only barrier in this kernel) ---
#pragma unroll
  for (int rep = 0; rep < 16; ++rep) {
    const int G = rep * 256 + tid;
    const int row = G >> 6, g = G & 63;
    *(short8*)(BsB + row * 1024 + (((g ^ row) & 63) << 4)) =
        *(const short8*)(WT + (size_t)(n0 + row) * Hdim + g * 8);
  }
  __syncthreads();

  float4v acc[4][2];
#pragma unroll
  for (int i = 0; i < 4; ++i)
#pragma unroll
    for (int j = 0; j < 2; ++j)
      acc[i][j] = (float4v){0.f, 0.f, 0.f, 0.f};

  // lane's A base: row kk0 + wm*64 + lm (+ mt*16), k-offset lq*8
  const float* arow = c_input + (size_t)(kk0 + wm * 64 + lm) * Hdim + lq * 8;

  // cur/nxt: [mt][0..1] = ks=0 floats j0..7, [2..3] = ks=1 (k+32)
  float4v cur[4][4], nxt[4][4];
#pragma unroll
  for (int mt = 0; mt < 4; ++mt) {
    const float* p = arow + (size_t)(mt * 16) * Hdim;
    cur[mt][0] = *(const float4v*)p;
    cur[mt][1] = *(const float4v*)(p + 4);
    cur[mt][2] = *(const float4v*)(p + 32);
    cur[mt][3] = *(const float4v*)(p + 36);
  }

#pragma unroll 1
  for (int it = 0; it < 8; ++it) {
    if (it < 7) {
      const int d0 = (it + 1) * 64;
#pragma unroll
      for (int mt = 0; mt < 4; ++mt) {
        const float* p = arow + (size_t)(mt * 16) * Hdim + d0;
        nxt[mt][0] = *(const float4v*)p;
        nxt[mt][1] = *(const float4v*)(p + 4);
        nxt[mt][2] = *(const float4v*)(p + 32);
        nxt[mt][3] = *(const float4v*)(p + 36);
      }
    }
#pragma unroll
    for (int ks = 0; ks < 2; ++ks) {
      short8 a[4];
#pragma unroll
      for (int mt = 0; mt < 4; ++mt) {
        union { unsigned int u[4]; short8 s; } af;
        af.u[0] = pack_bf16_trunc(cur[mt][ks * 2][0], cur[mt][ks * 2][1]);
        af.u[1] = pack_bf16_trunc(cur[mt][ks * 2][2], cur[mt][ks * 2][3]);
        af.u[2] = pack_bf16_trunc(cur[mt][ks * 2 + 1][0], cur[mt][ks * 2 + 1][1]);
        af.u[3] = pack_bf16_trunc(cur[mt][ks * 2 + 1][2], cur[mt][ks * 2 + 1][3]);
        a[mt] = af.s;
      }
      short8 bfr[2];
#pragma unroll
      for (int nt = 0; nt < 2; ++nt) {
        const int row = wn * 32 + nt * 16 + lm;
        const int G = it * 8 + ks * 4 + lq;
        bfr[nt] = *(const short8*)(BsB + row * 1024 + (((G ^ row) & 63) << 4));
      }
#pragma unroll
      for (int mt = 0; mt < 4; ++mt)
#pragma unroll
        for (int nt = 0; nt < 2; ++nt)
          acc[mt][nt] = __builtin_amdgcn_mfma_f32_16x16x32_bf16(a[mt], bfr[nt], acc[mt][nt], 0, 0, 0);
    }
#pragma unroll
    for (int mt = 0; mt < 4; ++mt)
#pragma unroll
      for (int q = 0; q < 4; ++q)
        cur[mt][q] = nxt[mt][q];
  }

  // epilogue (no barriers): alpha = sigmoid(acc + awi[n]); atomically accumulate
#pragma unroll
  for (int nt = 0; nt < 2; ++nt) {
    const int n = n0 + wn * 32 + nt * 16 + lm;
    float aw = 0.f;
#pragma unroll
    for (int dc = 0; dc < 8; ++dc) aw += awi_part[dc * Hdim + n];
    float sw = 0.f, swc = 0.f;
#pragma unroll
    for (int mt = 0; mt < 4; ++mt) {
      const int mrow = kk0 + wm * 64 + mt * 16 + lq * 4;
#pragma unroll
      for (int r = 0; r < 4; ++r) {
        float v = acc[mt][nt][r] + aw;
        float alpha = 1.f / (1.f + __expf(-v));
        float e = __expf(alpha);
        float c = c_input[(size_t)(mrow + r) * Hdim + n];  // L2-hot (just streamed)
        sw  += e;
        swc += e * c;
      }
    }
    sw  += __shfl_xor(sw, 16, 64);
    sw  += __shfl_xor(sw, 32, 64);
    swc += __shfl_xor(swc, 16, 64);
    swc += __shfl_xor(swc, 32, 64);
    if (lq == 0) {
      atomicAdd(&sw_g[n], sw);
      atomicAdd(&swc_g[n], swc);
    }
  }
}

// ---- launch 3: final merge (1 block x 512) ----
__global__ __launch_bounds__(512) void finalize_kernel(
    const float* __restrict__ sw_g, const float* __restrict__ swc_g,
    const float* __restrict__ gates_part, const float* __restrict__ bias,
    float* __restrict__ out) {
  const int h = threadIdx.x;  // 0..511
  float ip = 0.f, op = 0.f, gp = 0.f;
#pragma unroll
  for (int dc = 0; dc < 8; ++dc) {
    ip += gates_part[dc * 1536 + h];
    op += gates_part[dc * 1536 + 512 + h];
    gp += gates_part[dc * 1536 + 1024 + h];
  }
  ip += bias[h]; op += bias[512 + h]; gp += bias[1024 + h];
  float sw = sw_g[h], swc = swc_g[h];
  float ei = expf(1.f / (1.f + expf(-ip)));   // exp(sigmoid(i))
  float g  = tanhf(gp);
  float o  = 1.f / (1.f + expf(-op));
  float denom = ei + sw + 1e-12f;
  float c1 = (ei * g + swc) / denom;
  float h1 = o * tanhf(c1);
  out[h]       = h1;
  out[512 + h] = c1;
}

extern "C" void kernel_launch(void* const* d_in, const int* in_sizes, int n_in,
                              void* d_out, int out_size, void* d_ws, size_t ws_size,
                              hipStream_t stream) {
  const float* input_  = (const float*)d_in[0];
  const float* c_input = (const float*)d_in[1];
  const float* h_0     = (const float*)d_in[2];
  /* d_in[3] = c_0: unused by the reference's taken branch */
  const float* w_ih    = (const float*)d_in[4];
  const float* w_hh    = (const float*)d_in[5];
  const float* bias    = (const float*)d_in[6];
  const float* a_w_ih  = (const float*)d_in[7];
  const float* a_w_hh  = (const float*)d_in[8];

  char* ws = (char*)d_ws;
  float* sw_g       = (float*)ws;                      // 2 KB
  float* swc_g      = (float*)(ws + 2048);             // 2 KB
  float* gates_part = (float*)(ws + 4096);             // 8*1536*4 = 48 KB
  float* awi_part   = (float*)(ws + 4096 + 49152);     // 8*512*4 = 16 KB
  bf16*  WT         = (bf16*)(ws + 4096 + 65536);      // 512 KB

  hipMemsetAsync(ws, 0, 4096, stream);                 // zero sw_g/swc_g
  hipLaunchKernelGGL(prep_wt_kernel, dim3(320), dim3(256), 0, stream,
                     input_, h_0, w_ih, w_hh, a_w_ih, a_w_hh, gates_part, awi_part, WT);
  hipLaunchKernelGGL(gemm_reduce_kernel, dim3(2048), dim3(256), 65536, stream,
                     c_input, WT, awi_part, sw_g, swc_g);
  hipLaunchKernelGGL(finalize_kernel, dim3(1), dim3(512), 0, stream,
                     sw_g, swc_g, gates_part, bias, (float*)d_out);
}